// Round 10
// baseline (82.567 us; speedup 1.0000x reference)
//
#include <hip/hip_runtime.h>

#define WINDOW 11
#define H 512
#define W 512
#define OH 502            // H - WINDOW + 1
#define OW 502
#define NCH 3
#define BATCH 8
#define RSTRIPE 32
#define NSTRIPES 16       // 15 x 32 rows + 1 x 22 rows (both even trip counts)
#define NGRP 3            // col groups, float4 lanes: bases 0 / 244 / 256
#define WAVES_PER_IMG (NSTRIPES * NGRP)                 // 48
#define NWAVES (BATCH * NCH * WAVES_PER_IMG)            // 1152
#define WAVES_PER_BATCH (NCH * WAVES_PER_IMG)           // 144
#define NXCD 8
#define CHUNK (NWAVES / NXCD)                           // 144 = one batch per XCD
#define CNT_OFFSET 8192   // byte offset of counters in d_ws

#define NPIX_PER_BATCH (3.0f * 502.0f * 502.0f)   // 756012

// ---- gfx9 DPP inclusive wave scan (64 lanes), VALU-pipe only ----
template <int CTRL, int RM>
__device__ __forceinline__ float scan_step(float x) {
    int s = __builtin_amdgcn_update_dpp(0, __builtin_bit_cast(int, x),
                                        CTRL, RM, 0xf, false);
    return x + __builtin_bit_cast(float, s);
}
__device__ __forceinline__ float wave_iscan(float x) {
    x = scan_step<0x111, 0xf>(x);   // row_shr:1
    x = scan_step<0x112, 0xf>(x);   // row_shr:2
    x = scan_step<0x114, 0xf>(x);   // row_shr:4
    x = scan_step<0x118, 0xf>(x);   // row_shr:8
    x = scan_step<0x142, 0xa>(x);   // row_bcast:15 -> rows 1,3
    x = scan_step<0x143, 0xc>(x);   // row_bcast:31 -> rows 2,3
    return x;
}

__device__ __forceinline__ float4 f4add(float4 a, float4 b) {
    return make_float4(a.x + b.x, a.y + b.y, a.z + b.z, a.w + b.w);
}
__device__ __forceinline__ float4 f4sub(float4 a, float4 b) {
    return make_float4(a.x - b.x, a.y - b.y, a.z - b.z, a.w - b.w);
}
__device__ __forceinline__ float4 shfl4(float4 v, int src) {
    return make_float4(__shfl(v.x, src, 64), __shfl(v.y, src, 64),
                       __shfl(v.z, src, 64), __shfl(v.w, src, 64));
}

__device__ __forceinline__ float ssim_from(float sx, float sy, float s2, float sxy) {
    const float n = 121.0f;
    const float inv_n = 1.0f / 121.0f;
    const float inv_nm1 = 1.0f / 120.0f;
    const float c1 = 1e-4f;   // (0.01)^2
    const float c2 = 9e-4f;   // (0.03)^2
    float mx  = sx * inv_n;
    float my  = sy * inv_n;
    float mxy = mx * my;
    float m2  = mx * mx + my * my;
    float cov = (sxy - n * mxy) * inv_nm1;   // covariance
    float v2  = (s2  - n * m2)  * inv_nm1;   // vx + vy
    float num = (2.f * mxy + c1) * (2.f * cov + c2);
    float den = (m2 + c1) * (v2 + c2);
    return num * __builtin_amdgcn_rcpf(den);  // den >= 9e-8, rel err ~1e-7
}

__global__ __launch_bounds__(64) void ssim_main(const float* __restrict__ x,
                                                const float* __restrict__ y,
                                                float* __restrict__ partials,
                                                int* __restrict__ cnt,
                                                float* __restrict__ out) {
    const int lane = threadIdx.x & 63;

    // XCD-chunked bijective swizzle: one batch (3 images, all grps+stripes)
    // per XCD -> all halo overlap and old-row re-reads are XCD-L2-local.
    const int wg    = blockIdx.x;               // 0..1151, round-robins XCDs
    const int w_lin = (wg % NXCD) * CHUNK + wg / NXCD;

    const int img = w_lin / WAVES_PER_IMG;      // b*NCH + c
    const int rem = w_lin % WAVES_PER_IMG;
    const int grp = rem / NSTRIPES;
    const int rs  = rem % NSTRIPES;             // stripe minor -> L2-contiguous
    const int batch = w_lin / WAVES_PER_BATCH;

    const int i0 = rs * RSTRIPE;
    const int i1 = min(i0 + RSTRIPE, OH);       // 32 rows; stripe 15: 22 (even)
    // 4-aligned group bases; stage windows always inside [0,512)
    const int base  = (grp == 0) ? 0 : (grp == 1 ? 244 : 256);
    const int outLo = (grp == 0) ? 0 : (grp == 1 ? 246 : 490);
    const int outHi = (grp == 0) ? 245 : (grp == 1 ? 489 : 501);

    const int col = base + 4 * lane;            // this lane's 4 columns
    const bool m0a = (col     >= outLo) & (col     <= outHi);
    const bool m1a = (col + 1 >= outLo) & (col + 1 <= outHi);
    const bool m2a = (col + 2 >= outLo) & (col + 2 <= outHi);
    const bool m3a = (col + 3 >= outLo) & (col + 3 <= outHi);

    const float* __restrict__ xc = x + (size_t)img * H * W + col;
    const float* __restrict__ yc = y + (size_t)img * H * W + col;

    // --- init: per-column {sx, sy, sxx+syy, sxy} sums for rows i0..i0+10 ---
    float4 v0 = make_float4(0.f, 0.f, 0.f, 0.f);   // col+0
    float4 v1 = v0, v2 = v0, v3 = v0;              // col+1..3
#pragma unroll
    for (int r = 0; r < WINDOW; ++r) {
        float4 a = *(const float4*)(xc + (size_t)(i0 + r) * W);
        float4 b = *(const float4*)(yc + (size_t)(i0 + r) * W);
        v0.x += a.x; v0.y += b.x; v0.z += a.x * a.x + b.x * b.x; v0.w += a.x * b.x;
        v1.x += a.y; v1.y += b.y; v1.z += a.y * a.y + b.y * b.y; v1.w += a.y * b.y;
        v2.x += a.z; v2.y += b.z; v2.z += a.z * a.z + b.z * b.z; v2.w += a.z * b.z;
        v3.x += a.w; v3.y += b.w; v3.z += a.w * a.w + b.w * b.w; v3.w += a.w * b.w;
    }

#define LD(j, xo, yo, xn, yn) do {                                  \
        int jc_ = min((j), H - 1);                                   \
        int rn_ = min((j) + WINDOW, H - 1);                          \
        xo = *(const float4*)(xc + (size_t)jc_ * W);                 \
        yo = *(const float4*)(yc + (size_t)jc_ * W);                 \
        xn = *(const float4*)(xc + (size_t)rn_ * W);                 \
        yn = *(const float4*)(yc + (size_t)rn_ * W);                 \
    } while (0)

    // one column's slide update: v <- v + contrib(new) - contrib(old)
#define SL1(v, cN, cO, dN, dO) do {                                  \
        v.x += cN - cO;                                              \
        v.y += dN - dO;                                              \
        v.z += cN * cN + dN * dN - cO * cO - dO * dO;                \
        v.w += cN * dN - cO * dO;                                    \
    } while (0)

#define SLIDE(xo, yo, xn, yn) do {                                   \
        SL1(v0, xn.x, xo.x, yn.x, yo.x);                             \
        SL1(v1, xn.y, xo.y, yn.y, yo.y);                             \
        SL1(v2, xn.z, xo.z, yn.z, yo.z);                             \
        SL1(v3, xn.w, xo.w, yn.w, yo.w);                             \
    } while (0)

    float acc = 0.f;

    // Window sums via wave scan. P = global col prefix; for lane l:
    //   L = S - T (prefix before col), m0 = L+v0, m01 = m0+v1, m012 = m01+v2
    //   W[col+0] = m012[l+2] - L       W[col+1] = S[l+2]   - m0
    //   W[col+2] = m0[l+3]   - m01     W[col+3] = m01[l+3] - m012
#define COMPUTE() do {                                                        \
        float4 T = f4add(f4add(v0, v1), f4add(v2, v3));                       \
        float4 S = make_float4(wave_iscan(T.x), wave_iscan(T.y),              \
                               wave_iscan(T.z), wave_iscan(T.w));             \
        float4 L    = f4sub(S, T);                                            \
        float4 p0   = f4add(L, v0);                                           \
        float4 p01  = f4add(p0, v1);                                          \
        float4 p012 = f4add(p01, v2);                                         \
        float4 A012 = shfl4(p012, lane + 2);                                  \
        float4 AS   = shfl4(S,    lane + 2);                                  \
        float4 B0   = shfl4(p0,   lane + 3);                                  \
        float4 B01  = shfl4(p01,  lane + 3);                                  \
        float4 W0 = f4sub(A012, L);                                           \
        float4 W1 = f4sub(AS,   p0);                                          \
        float4 W2 = f4sub(B0,   p01);                                         \
        float4 W3 = f4sub(B01,  p012);                                        \
        acc += m0a ? ssim_from(W0.x, W0.y, W0.z, W0.w) : 0.f;                 \
        acc += m1a ? ssim_from(W1.x, W1.y, W1.z, W1.w) : 0.f;                 \
        acc += m2a ? ssim_from(W2.x, W2.y, W2.z, W2.w) : 0.f;                 \
        acc += m3a ? ssim_from(W3.x, W3.y, W3.z, W3.w) : 0.f;                 \
    } while (0)

    // --- depth-2 software-pipelined main loop (best known structure, R6) ---
    float4 xoA, yoA, xnA, ynA, xoB, yoB, xnB, ynB;
    LD(i0,     xoA, yoA, xnA, ynA);
    LD(i0 + 1, xoB, yoB, xnB, ynB);
    for (int i = i0; i < i1; i += 2) {
        COMPUTE();                       // row i
        SLIDE(xoA, yoA, xnA, ynA);       // -> window for row i+1
        LD(i + 2, xoA, yoA, xnA, ynA);   // prefetch iter i+2 (row clamped)
        COMPUTE();                       // row i+1
        SLIDE(xoB, yoB, xnB, ynB);       // -> window for row i+2
        LD(i + 3, xoB, yoB, xnB, ynB);   // prefetch iter i+3 (row clamped)
    }

    // --- per-wave reduction (fixed order, deterministic) ---
    for (int off = 32; off > 0; off >>= 1)
        acc += __shfl_down(acc, off, 64);

    // --- fused final reduce: last-arriving wave per batch sums its batch ---
    int elected = 0;
    if (lane == 0) {
        partials[w_lin] = acc;
        __threadfence();   // make partial visible device-wide (release)
        int old = __hip_atomic_fetch_add(&cnt[batch], 1, __ATOMIC_ACQ_REL,
                                         __HIP_MEMORY_SCOPE_AGENT);
        elected = (old == WAVES_PER_BATCH - 1);
    }
    elected = __shfl(elected, 0, 64);
    if (elected) {
        __threadfence();   // acquire: invalidate stale cached partials
        const float* pb = partials + batch * WAVES_PER_BATCH;
        float s = pb[lane] + pb[lane + 64];          // fixed-order addends
        if (lane < WAVES_PER_BATCH - 128) s += pb[lane + 128];
        for (int off = 32; off > 0; off >>= 1)
            s += __shfl_down(s, off, 64);
        if (lane == 0)
            out[batch] = (1.0f - s / NPIX_PER_BATCH) * 0.5f;
    }
}

extern "C" void kernel_launch(void* const* d_in, const int* in_sizes, int n_in,
                              void* d_out, int out_size, void* d_ws, size_t ws_size,
                              hipStream_t stream) {
    const float* x = (const float*)d_in[0];
    const float* y = (const float*)d_in[1];
    float* out      = (float*)d_out;
    float* partials = (float*)d_ws;                       // 1152 floats
    int*   cnt      = (int*)((char*)d_ws + CNT_OFFSET);   // 8 ints

    hipMemsetAsync(cnt, 0, BATCH * sizeof(int), stream);  // capture-safe
    ssim_main<<<NWAVES, 64, 0, stream>>>(x, y, partials, cnt, out);
}